// Round 7
// baseline (1377.155 us; speedup 1.0000x reference)
//
#include <hip/hip_runtime.h>

// ---------------------------------------------------------------------------
// GAT fraud detector, round 7:
//  - agg kernels: persistent waves, one node per wave, halves combined by one
//    shfl_xor(32) (no LDS/barriers in node loop), bias preloaded per wave.
//  - BN stats fused into agg epilogue (register accumulators across nodes,
//    one LDS flush per block) -> bn_stats kernels removed.
//  - BN split restored to round-5 shape (bn_final tiny + bn_apply 256 blocks);
//    round-6's NB_RED=64 starved bn_stats (the 584->611 regression).
//  - GEMM / prep / CSR unchanged.
// ---------------------------------------------------------------------------

typedef unsigned int uint;
typedef unsigned short ushort;

#define NEG_SLOPE 0.2f
#define BN_EPS 1e-5f
#define NB_AGG 1024   // persistent agg blocks (x4 waves = 4096 waves)
#define NB_POOL 256   // pool partial blocks

__device__ __forceinline__ float bf2f(uint u) { return __uint_as_float(u << 16); }
__device__ __forceinline__ ushort f2bf(float f) {
    uint u = __float_as_uint(f);
    u += 0x7fff + ((u >> 16) & 1);   // round-nearest-even
    return (ushort)(u >> 16);
}
__device__ __forceinline__ float lrelu(float x) { return x > 0.f ? x : NEG_SLOPE * x; }

// ---------------- fused prep: cvt x -> bf16 (padded), transpose weights, histogram ----------------

__global__ void prep_kernel(const float* __restrict__ x, ushort* __restrict__ xb,
                            int total_real, int total_pad,
                            const float* __restrict__ W0, ushort* __restrict__ w0t,
                            const float* __restrict__ W1, ushort* __restrict__ w1t,
                            const float* __restrict__ W2, ushort* __restrict__ w2t,
                            const int* __restrict__ ei, int* __restrict__ deg, int E) {
    int i = blockIdx.x * blockDim.x + threadIdx.x;
    if (i < total_pad) {
        xb[i] = (i < total_real) ? f2bf(x[i]) : (ushort)0;
        return;
    }
    int j = i - total_pad;
    if (j < 32768) {                        // W0: K=128,F=256
        int n = j / 128, k = j - n * 128;
        w0t[j] = f2bf(W0[(size_t)k * 256 + n]);
        return;
    }
    j -= 32768;
    if (j < 65536) {                        // W1: K=256,F=256
        int n = j / 256, k = j - n * 256;
        w1t[j] = f2bf(W1[(size_t)k * 256 + n]);
        return;
    }
    j -= 65536;
    if (j < 16384) {                        // W2: K=256,F=64
        int n = j / 256, k = j - n * 256;
        w2t[j] = f2bf(W2[(size_t)k * 64 + n]);
        return;
    }
    j -= 16384;
    if (j < E) atomicAdd(&deg[ei[E + j]], 1);
}

// ---------------- CSR scan + scatter ----------------

__global__ void scan_part(const int* __restrict__ deg, int* __restrict__ offsets,
                          int* __restrict__ bsum, int N) {
    __shared__ int sh[256];
    int t = threadIdx.x;
    int base = blockIdx.x * 1024 + t * 4;
    int v0 = (base + 0 < N) ? deg[base + 0] : 0;
    int v1 = (base + 1 < N) ? deg[base + 1] : 0;
    int v2 = (base + 2 < N) ? deg[base + 2] : 0;
    int v3 = (base + 3 < N) ? deg[base + 3] : 0;
    int s = v0 + v1 + v2 + v3;
    sh[t] = s;
    __syncthreads();
    for (int off = 1; off < 256; off <<= 1) {
        int y = (t >= off) ? sh[t - off] : 0;
        __syncthreads();
        sh[t] += y;
        __syncthreads();
    }
    int p = sh[t] - s;
    if (base + 0 < N) offsets[base + 0] = p;
    p += v0;
    if (base + 1 < N) offsets[base + 1] = p;
    p += v1;
    if (base + 2 < N) offsets[base + 2] = p;
    p += v2;
    if (base + 3 < N) offsets[base + 3] = p;
    if (t == 255) bsum[blockIdx.x] = sh[255];
}

__global__ void scan_add(int* __restrict__ offsets, int* __restrict__ cursor,
                         const int* __restrict__ bsum, int N) {
    __shared__ int sadd;
    int nb = gridDim.x;
    if (threadIdx.x == 0) {
        int run = 0;
        for (int b = 0; b < (int)blockIdx.x; ++b) run += bsum[b];
        sadd = run;
        if ((int)blockIdx.x == nb - 1) {
            int tot = run;
            for (int b = blockIdx.x; b < nb; ++b) tot += bsum[b];
            offsets[N] = tot;
        }
    }
    __syncthreads();
    int add = sadd;
    int base = blockIdx.x * 1024 + threadIdx.x * 4;
#pragma unroll
    for (int k = 0; k < 4; ++k) {
        int i = base + k;
        if (i < N) { int v = offsets[i] + add; offsets[i] = v; cursor[i] = v; }
    }
}

__global__ void scatter_kernel(const int* __restrict__ ei, int* __restrict__ cursor,
                               int* __restrict__ srcs, int E) {
    int e = blockIdx.x * blockDim.x + threadIdx.x;
    if (e < E) {
        int s = ei[e];
        int d = ei[E + e];
        int p = atomicAdd(&cursor[d], 1);
        srcs[p] = s;
    }
}

// ---------------- bf16 MFMA GEMM with fused sd epilogue ----------------

typedef __attribute__((ext_vector_type(8))) short bf16x8;
typedef __attribute__((ext_vector_type(4))) float floatx4;

template <int BN, int H>
__launch_bounds__(256)
__global__ void mfma_gemm_bt(const ushort* __restrict__ A, const ushort* __restrict__ Bt,
                             ushort* __restrict__ C, const float* __restrict__ asrc,
                             const float* __restrict__ adst, float* __restrict__ sv,
                             float* __restrict__ dv, int K, int Nn) {
    constexpr int WCOLS = (BN == 128) ? 2 : 1;
    constexpr int WROWS = 4 / WCOLS;
    constexpr int MT = 128 / (WROWS * 16);
    constexpr int NT = BN / (WCOLS * 16);
    constexpr int BCALLS = (BN * 32 * 2) / 4096;

    __shared__ ushort As[128 * 32];
    __shared__ ushort Bs[BN * 32];

    int t = threadIdx.x;
    int w = t >> 6, l = t & 63;
    int row0 = blockIdx.x * 128;
    int col0 = blockIdx.y * BN;
    int wr = (w / WCOLS) * (MT * 16);
    int wc = (w % WCOLS) * (NT * 16);

    floatx4 acc[MT][NT];
#pragma unroll
    for (int mi = 0; mi < MT; ++mi)
#pragma unroll
        for (int ni = 0; ni < NT; ++ni)
#pragma unroll
            for (int r = 0; r < 4; ++r) acc[mi][ni][r] = 0.f;

    int mrow = l & 15;
    int kc = (l >> 4) * 8;

    for (int kt = 0; kt < K; kt += 32) {
#pragma unroll
        for (int c = 0; c < 2; ++c) {
            int idx = c * 256 + t;
            const ushort* gp = A + (size_t)(row0 + (idx >> 2)) * K + kt + (idx & 3) * 8;
            __builtin_amdgcn_global_load_lds(
                (const __attribute__((address_space(1))) void*)gp,
                (__attribute__((address_space(3))) void*)(As + (idx & ~63) * 8),
                16, 0, 0);
        }
#pragma unroll
        for (int c = 0; c < BCALLS; ++c) {
            int idx = c * 256 + t;
            const ushort* gp = Bt + (size_t)(col0 + (idx >> 2)) * K + kt + (idx & 3) * 8;
            __builtin_amdgcn_global_load_lds(
                (const __attribute__((address_space(1))) void*)gp,
                (__attribute__((address_space(3))) void*)(Bs + (idx & ~63) * 8),
                16, 0, 0);
        }
        __syncthreads();

        bf16x8 af[MT], bfr[NT];
#pragma unroll
        for (int mi = 0; mi < MT; ++mi)
            af[mi] = *(const bf16x8*)&As[(wr + mi * 16 + mrow) * 32 + kc];
#pragma unroll
        for (int ni = 0; ni < NT; ++ni)
            bfr[ni] = *(const bf16x8*)&Bs[(wc + ni * 16 + mrow) * 32 + kc];
#pragma unroll
        for (int mi = 0; mi < MT; ++mi)
#pragma unroll
            for (int ni = 0; ni < NT; ++ni)
                acc[mi][ni] = __builtin_amdgcn_mfma_f32_16x16x32_bf16(
                    af[mi], bfr[ni], acc[mi][ni], 0, 0, 0);
        __syncthreads();
    }

    // C store (C/D layout: col=lane&15, row=(lane>>4)*4+reg)
#pragma unroll
    for (int mi = 0; mi < MT; ++mi) {
        int rbase = row0 + wr + mi * 16 + (l >> 4) * 4;
#pragma unroll
        for (int ni = 0; ni < NT; ++ni) {
            int col = col0 + wc + ni * 16 + (l & 15);
#pragma unroll
            for (int r = 0; r < 4; ++r)
                C[(size_t)(rbase + r) * Nn + col] = f2bf(acc[mi][ni][r]);
        }
    }

    // fused sd: this wave's NT*16 cols lie in exactly one head (64 cols).
    float av[NT], bv[NT];
#pragma unroll
    for (int ni = 0; ni < NT; ++ni) {
        int ch = col0 + wc + ni * 16 + (l & 15);
        av[ni] = asrc[ch];
        bv[ni] = adst[ch];
    }
    int gh = (col0 + wc) >> 6;
#pragma unroll
    for (int mi = 0; mi < MT; ++mi) {
#pragma unroll
        for (int r = 0; r < 4; ++r) {
            float s = 0.f, d = 0.f;
#pragma unroll
            for (int ni = 0; ni < NT; ++ni) {
                float hv = acc[mi][ni][r];
                s += hv * av[ni];
                d += hv * bv[ni];
            }
#pragma unroll
            for (int m = 8; m >= 1; m >>= 1) {
                s += __shfl_xor(s, m);
                d += __shfl_xor(d, m);
            }
            if ((l & 15) == 0) {
                int row = row0 + wr + mi * 16 + (l >> 4) * 4 + r;
                sv[row * H + gh] = s;
                dv[row * H + gh] = d;
            }
        }
    }
}

// ---------------- aggregation: persistent waves, one node per wave ----------------
// Wave = 2 edge-slots x 32 lanes; lane owns 8 channels (uint4/edge). Slots
// combined by shfl_xor(32). 2-deep unroll per slot -> 4 gathers in flight.
// BN stats (sum, sumsq of output) accumulated in registers across nodes,
// flushed once per block via LDS -> per-block partials ps/pq.

__launch_bounds__(256)
__global__ void agg4_kernel(const ushort* __restrict__ hb, const float* __restrict__ sv,
                            const float* __restrict__ dv, const int* __restrict__ offsets,
                            const int* __restrict__ srcs, const float* __restrict__ bias,
                            ushort* __restrict__ zb, float* __restrict__ ps,
                            float* __restrict__ pq, int N) {
    __shared__ float lds_s[256], lds_q[256];
    int t = threadIdx.x;
    lds_s[t] = 0.f; lds_q[t] = 0.f;
    __syncthreads();

    int l = t & 63;
    int half = l >> 5, gl = l & 31, head = gl >> 3;
    int cbase = gl * 8;
    int gw = blockIdx.x * 4 + (t >> 6);
    int nw = gridDim.x * 4;

    float bi[8];
    *(float4*)&bi[0] = *(const float4*)&bias[cbase];
    *(float4*)&bi[4] = *(const float4*)&bias[cbase + 4];

    float szm[8] = {}, sqm[8] = {};

    for (int i = gw; i < N; i += nw) {
        int beg = offsets[i], end = offsets[i + 1];
        float d_i = dv[i * 4 + head];
        float acc[8] = {};
        float den = 0.f;

        int j0 = beg + half, j1 = j0 + 2;
        while (j1 < end) {
            int s0 = srcs[j0], s1 = srcs[j1];
            float sv0 = sv[s0 * 4 + head], sv1 = sv[s1 * 4 + head];
            uint4 q0 = *(const uint4*)&hb[(size_t)s0 * 256 + cbase];
            uint4 q1 = *(const uint4*)&hb[(size_t)s1 * 256 + cbase];
            float w0 = __expf(fminf(lrelu(sv0 + d_i), 60.f));
            float w1 = __expf(fminf(lrelu(sv1 + d_i), 60.f));
            den += w0 + w1;
            uint pr0[4] = {q0.x, q0.y, q0.z, q0.w};
            uint pr1[4] = {q1.x, q1.y, q1.z, q1.w};
#pragma unroll
            for (int k = 0; k < 4; ++k) {
                acc[2 * k]     += w0 * bf2f(pr0[k] & 0xffffu) + w1 * bf2f(pr1[k] & 0xffffu);
                acc[2 * k + 1] += w0 * bf2f(pr0[k] >> 16)     + w1 * bf2f(pr1[k] >> 16);
            }
            j0 += 4; j1 += 4;
        }
        if (j0 < end) {
            int s0 = srcs[j0];
            float sv0 = sv[s0 * 4 + head];
            uint4 q0 = *(const uint4*)&hb[(size_t)s0 * 256 + cbase];
            float w0 = __expf(fminf(lrelu(sv0 + d_i), 60.f));
            den += w0;
            uint pr0[4] = {q0.x, q0.y, q0.z, q0.w};
#pragma unroll
            for (int k = 0; k < 4; ++k) {
                acc[2 * k]     += w0 * bf2f(pr0[k] & 0xffffu);
                acc[2 * k + 1] += w0 * bf2f(pr0[k] >> 16);
            }
        }

        // combine the two slots (both halves end with full sums)
        den += __shfl_xor(den, 32);
#pragma unroll
        for (int k = 0; k < 8; ++k) acc[k] += __shfl_xor(acc[k], 32);

        // self loop + output
        float wself = __expf(fminf(lrelu(sv[i * 4 + head] + d_i), 60.f));
        uint4 qs = *(const uint4*)&hb[(size_t)i * 256 + cbase];
        float rden = 1.f / (den + wself + 1e-16f);
        uint prs[4] = {qs.x, qs.y, qs.z, qs.w};
        float out[8];
#pragma unroll
        for (int k = 0; k < 4; ++k) {
            out[2 * k]     = (acc[2 * k]     + wself * bf2f(prs[k] & 0xffffu)) * rden + bi[2 * k];
            out[2 * k + 1] = (acc[2 * k + 1] + wself * bf2f(prs[k] >> 16))     * rden + bi[2 * k + 1];
        }
#pragma unroll
        for (int k = 0; k < 8; ++k) { szm[k] += out[k]; sqm[k] += out[k] * out[k]; }
        if (half == 0) {
            uint4 o;
            o.x = (uint)f2bf(out[0]) | ((uint)f2bf(out[1]) << 16);
            o.y = (uint)f2bf(out[2]) | ((uint)f2bf(out[3]) << 16);
            o.z = (uint)f2bf(out[4]) | ((uint)f2bf(out[5]) << 16);
            o.w = (uint)f2bf(out[6]) | ((uint)f2bf(out[7]) << 16);
            *(uint4*)&zb[(size_t)i * 256 + cbase] = o;
        }
    }

    if (half == 0) {
#pragma unroll
        for (int k = 0; k < 8; ++k) {
            atomicAdd(&lds_s[cbase + k], szm[k]);
            atomicAdd(&lds_q[cbase + k], sqm[k]);
        }
    }
    __syncthreads();
    ps[blockIdx.x * 256 + t] = lds_s[t];
    pq[blockIdx.x * 256 + t] = lds_q[t];
}

// H=1, F=64: wave = 4 slots x 16 lanes (uint2/edge), combine shfl 16 then 32.

__launch_bounds__(256)
__global__ void agg1_kernel(const ushort* __restrict__ hb, const float* __restrict__ sv,
                            const float* __restrict__ dv, const int* __restrict__ offsets,
                            const int* __restrict__ srcs, const float* __restrict__ bias,
                            ushort* __restrict__ zb, float* __restrict__ ps,
                            float* __restrict__ pq, int N) {
    __shared__ float lds_s[64], lds_q[64];
    int t = threadIdx.x;
    if (t < 64) { lds_s[t] = 0.f; lds_q[t] = 0.f; }
    __syncthreads();

    int l = t & 63;
    int slot = l >> 4, gl = l & 15;
    int cbase = gl * 4;
    int gw = blockIdx.x * 4 + (t >> 6);
    int nw = gridDim.x * 4;

    float bi[4];
    *(float4*)&bi[0] = *(const float4*)&bias[cbase];

    float szm[4] = {}, sqm[4] = {};

    for (int i = gw; i < N; i += nw) {
        int beg = offsets[i], end = offsets[i + 1];
        float d_i = dv[i];
        float acc[4] = {};
        float den = 0.f;

        int j0 = beg + slot, j1 = j0 + 4;
        while (j1 < end) {
            int s0 = srcs[j0], s1 = srcs[j1];
            float sv0 = sv[s0], sv1 = sv[s1];
            uint2 q0 = *(const uint2*)&hb[(size_t)s0 * 64 + cbase];
            uint2 q1 = *(const uint2*)&hb[(size_t)s1 * 64 + cbase];
            float w0 = __expf(fminf(lrelu(sv0 + d_i), 60.f));
            float w1 = __expf(fminf(lrelu(sv1 + d_i), 60.f));
            den += w0 + w1;
            acc[0] += w0 * bf2f(q0.x & 0xffffu) + w1 * bf2f(q1.x & 0xffffu);
            acc[1] += w0 * bf2f(q0.x >> 16)     + w1 * bf2f(q1.x >> 16);
            acc[2] += w0 * bf2f(q0.y & 0xffffu) + w1 * bf2f(q1.y & 0xffffu);
            acc[3] += w0 * bf2f(q0.y >> 16)     + w1 * bf2f(q1.y >> 16);
            j0 += 8; j1 += 8;
        }
        if (j0 < end) {
            int s0 = srcs[j0];
            float sv0 = sv[s0];
            uint2 q0 = *(const uint2*)&hb[(size_t)s0 * 64 + cbase];
            float w0 = __expf(fminf(lrelu(sv0 + d_i), 60.f));
            den += w0;
            acc[0] += w0 * bf2f(q0.x & 0xffffu);
            acc[1] += w0 * bf2f(q0.x >> 16);
            acc[2] += w0 * bf2f(q0.y & 0xffffu);
            acc[3] += w0 * bf2f(q0.y >> 16);
        }

#pragma unroll
        for (int k = 0; k < 4; ++k) {
            acc[k] += __shfl_xor(acc[k], 16);
            acc[k] += __shfl_xor(acc[k], 32);
        }
        den += __shfl_xor(den, 16);
        den += __shfl_xor(den, 32);

        float wself = __expf(fminf(lrelu(sv[i] + d_i), 60.f));
        uint2 qs = *(const uint2*)&hb[(size_t)i * 64 + cbase];
        float rden = 1.f / (den + wself + 1e-16f);
        float out[4];
        out[0] = (acc[0] + wself * bf2f(qs.x & 0xffffu)) * rden + bi[0];
        out[1] = (acc[1] + wself * bf2f(qs.x >> 16))     * rden + bi[1];
        out[2] = (acc[2] + wself * bf2f(qs.y & 0xffffu)) * rden + bi[2];
        out[3] = (acc[3] + wself * bf2f(qs.y >> 16))     * rden + bi[3];
#pragma unroll
        for (int k = 0; k < 4; ++k) { szm[k] += out[k]; sqm[k] += out[k] * out[k]; }
        if (slot == 0) {
            uint2 o;
            o.x = (uint)f2bf(out[0]) | ((uint)f2bf(out[1]) << 16);
            o.y = (uint)f2bf(out[2]) | ((uint)f2bf(out[3]) << 16);
            *(uint2*)&zb[(size_t)i * 64 + cbase] = o;
        }
    }

    if (slot == 0 && (l >> 4) == 0) {   // lanes 0..15 of each wave
#pragma unroll
        for (int k = 0; k < 4; ++k) {
            atomicAdd(&lds_s[cbase + k], szm[k]);
            atomicAdd(&lds_q[cbase + k], sqm[k]);
        }
    }
    __syncthreads();
    if (t < 64) {
        ps[blockIdx.x * 64 + t] = lds_s[t];
        pq[blockIdx.x * 64 + t] = lds_q[t];
    }
}

// ---------------- BN final (reduce per-block partials -> scale/shift) ----------------

__global__ void bn_final_kernel(const float* __restrict__ ps, const float* __restrict__ pq,
                                const float* __restrict__ g, const float* __restrict__ be,
                                float* __restrict__ scale, float* __restrict__ shift,
                                int N, int F, int NB) {
    int t = threadIdx.x;
    if (t < F) {
        float s = 0.f, q = 0.f;
        for (int b = 0; b < NB; ++b) { s += ps[b * F + t]; q += pq[b * F + t]; }
        float mean = s / (float)N;
        float var = q / (float)N - mean * mean;
        float sc = g[t] * rsqrtf(var + BN_EPS);
        scale[t] = sc;
        shift[t] = be[t] - sc * mean;
    }
}

template <int F>
__launch_bounds__(256)
__global__ void bn_apply_kernel(uint* __restrict__ x, const float* __restrict__ scale,
                                const float* __restrict__ shift, int totalPairs) {
    __shared__ float ssc[F], ssh[F];
    int t = threadIdx.x;
    if (t < F) { ssc[t] = scale[t]; ssh[t] = shift[t]; }
    __syncthreads();
    for (int i = blockIdx.x * 256 + t; i < totalPairs; i += gridDim.x * 256) {
        uint p = x[i];
        int c0 = (2 * i) & (F - 1);
        float v0 = fmaxf(bf2f(p & 0xffffu) * ssc[c0] + ssh[c0], 0.f);
        float v1 = fmaxf(bf2f(p >> 16) * ssc[c0 + 1] + ssh[c0 + 1], 0.f);
        x[i] = (uint)f2bf(v0) | ((uint)f2bf(v1) << 16);
    }
}

// ---------------- pooling (BN+ReLU fused, vectorized) ----------------

__launch_bounds__(256)
__global__ void pool_kernel(const ushort* __restrict__ y, const float* __restrict__ scale,
                            const float* __restrict__ shift, float* __restrict__ psum,
                            float* __restrict__ pmax, int N) {
    constexpr int F = 64, OCT = 8;
    __shared__ float lds_s[F];
    __shared__ uint lds_m[F];
    int t = threadIdx.x;
    if (t < F) { lds_s[t] = 0.f; lds_m[t] = 0u; }
    __syncthreads();

    int co = t % OCT;
    float sc[8], sh[8];
#pragma unroll
    for (int j = 0; j < 8; ++j) { sc[j] = scale[co * 8 + j]; sh[j] = shift[co * 8 + j]; }

    float s[8] = {}, m[8] = {};
    int total8 = N * F / 8;
    for (int idx = blockIdx.x * 256 + t; idx < total8; idx += NB_POOL * 256) {
        uint4 v = ((const uint4*)y)[idx];
        uint pr[4] = {v.x, v.y, v.z, v.w};
#pragma unroll
        for (int k = 0; k < 4; ++k) {
            float a = fmaxf(bf2f(pr[k] & 0xffffu) * sc[2 * k] + sh[2 * k], 0.f);
            float b = fmaxf(bf2f(pr[k] >> 16) * sc[2 * k + 1] + sh[2 * k + 1], 0.f);
            s[2 * k] += a;     m[2 * k] = fmaxf(m[2 * k], a);
            s[2 * k + 1] += b; m[2 * k + 1] = fmaxf(m[2 * k + 1], b);
        }
    }
#pragma unroll
    for (int j = 0; j < 8; ++j) {
        atomicAdd(&lds_s[co * 8 + j], s[j]);
        atomicMax(&lds_m[co * 8 + j], __float_as_uint(m[j]));
    }
    __syncthreads();
    if (t < F) {
        psum[blockIdx.x * F + t] = lds_s[t];
        pmax[blockIdx.x * F + t] = __uint_as_float(lds_m[t]);
    }
}

__global__ void classify_kernel(const float* __restrict__ psum, const float* __restrict__ pmax,
                                const float* __restrict__ Wc1, const float* __restrict__ bc1,
                                const float* __restrict__ Wc2, const float* __restrict__ bc2,
                                float* __restrict__ out, int N) {
    __shared__ float pooled[128];
    __shared__ float z[64];
    int t = threadIdx.x;   // 128 threads
    if (t < 64) {
        float s = 0.f;
        for (int b = 0; b < NB_POOL; ++b) s += psum[b * 64 + t];
        pooled[t] = s / (float)N;
    } else {
        int c = t - 64;
        float m = 0.f;
        for (int b = 0; b < NB_POOL; ++b) m = fmaxf(m, pmax[b * 64 + c]);
        pooled[t] = m;
    }
    __syncthreads();
    if (t < 64) {
        float a = bc1[t];
        for (int k = 0; k < 128; ++k) a += pooled[k] * Wc1[k * 64 + t];
        z[t] = a > 0.f ? a : 0.f;
    }
    __syncthreads();
    if (t < 2) {
        float a = bc2[t];
        for (int j = 0; j < 64; ++j) a += z[j] * Wc2[j * 2 + t];
        out[t] = a;
    }
}

// ---------------- driver ----------------

extern "C" void kernel_launch(void* const* d_in, const int* in_sizes, int n_in,
                              void* d_out, int out_size, void* d_ws, size_t ws_size,
                              hipStream_t stream) {
    const float* x   = (const float*)d_in[0];
    const int*   ei  = (const int*)d_in[1];
    const float* W0  = (const float*)d_in[2];  const float* b0  = (const float*)d_in[3];
    const float* as0 = (const float*)d_in[4];  const float* ad0 = (const float*)d_in[5];
    const float* g0  = (const float*)d_in[6];  const float* be0 = (const float*)d_in[7];
    const float* W1  = (const float*)d_in[8];  const float* b1  = (const float*)d_in[9];
    const float* as1 = (const float*)d_in[10]; const float* ad1 = (const float*)d_in[11];
    const float* g1  = (const float*)d_in[12]; const float* be1 = (const float*)d_in[13];
    const float* W2  = (const float*)d_in[14]; const float* b2  = (const float*)d_in[15];
    const float* as2 = (const float*)d_in[16]; const float* ad2 = (const float*)d_in[17];
    const float* g2  = (const float*)d_in[18]; const float* be2 = (const float*)d_in[19];
    const float* Wc1 = (const float*)d_in[20]; const float* bc1 = (const float*)d_in[21];
    const float* Wc2 = (const float*)d_in[22]; const float* bc2 = (const float*)d_in[23];
    float* out = (float*)d_out;

    const int N = in_sizes[0] / 128;            // 50000
    const int E = in_sizes[1] / 2;              // 800000
    const int Mpad = ((N + 127) / 128) * 128;   // 50048
    const int NB_SCAN = (N + 1023) / 1024;      // 49

    char* ws = (char*)d_ws;
    size_t o = 0;
    auto alloc = [&](size_t bytes) -> void* {
        void* p = ws + o;
        o = (o + bytes + 255) & ~(size_t)255;
        return p;
    };
    int*    deg     = (int*)alloc((size_t)N * 4);
    int*    offsets = (int*)alloc((size_t)(N + 1) * 4);
    int*    cursor  = (int*)alloc((size_t)N * 4);
    int*    srcs    = (int*)alloc((size_t)E * 4);
    int*    bsum    = (int*)alloc((size_t)NB_SCAN * 4);
    ushort* xb      = (ushort*)alloc((size_t)Mpad * 128 * 2);
    ushort* w0t     = (ushort*)alloc((size_t)256 * 128 * 2);
    ushort* w1t     = (ushort*)alloc((size_t)256 * 256 * 2);
    ushort* w2t     = (ushort*)alloc((size_t)64 * 256 * 2);
    ushort* hb      = (ushort*)alloc((size_t)Mpad * 256 * 2);
    ushort* zb      = (ushort*)alloc((size_t)Mpad * 256 * 2);
    float*  sv      = (float*)alloc((size_t)Mpad * 4 * 4);
    float*  dv      = (float*)alloc((size_t)Mpad * 4 * 4);
    float*  ps      = (float*)alloc((size_t)NB_AGG * 256 * 4);
    float*  pq      = (float*)alloc((size_t)NB_AGG * 256 * 4);
    float*  scale   = (float*)alloc(256 * 4);
    float*  shift   = (float*)alloc(256 * 4);
    float*  psum    = (float*)alloc((size_t)NB_POOL * 64 * 4);
    float*  pmax    = (float*)alloc((size_t)NB_POOL * 64 * 4);

    // ---- prep (cvt + transpose + histogram) ----
    hipMemsetAsync(deg, 0, (size_t)N * 4, stream);
    int prep_total = Mpad * 128 + 32768 + 65536 + 16384 + E;
    prep_kernel<<<(prep_total + 255) / 256, 256, 0, stream>>>(
        x, xb, N * 128, Mpad * 128, W0, w0t, W1, w1t, W2, w2t, ei, deg, E);

    // ---- CSR scan + scatter ----
    scan_part<<<NB_SCAN, 256, 0, stream>>>(deg, offsets, bsum, N);
    scan_add<<<NB_SCAN, 256, 0, stream>>>(offsets, cursor, bsum, N);
    scatter_kernel<<<(E + 255) / 256, 256, 0, stream>>>(ei, cursor, srcs, E);

    // ---- layer 0 ----
    {
        dim3 gg(Mpad / 128, 2);
        mfma_gemm_bt<128, 4><<<gg, 256, 0, stream>>>(xb, w0t, hb, as0, ad0, sv, dv, 128, 256);
        agg4_kernel<<<NB_AGG, 256, 0, stream>>>(hb, sv, dv, offsets, srcs, b0, zb, ps, pq, N);
        bn_final_kernel<<<1, 256, 0, stream>>>(ps, pq, g0, be0, scale, shift, N, 256, NB_AGG);
        bn_apply_kernel<256><<<256, 256, 0, stream>>>((uint*)zb, scale, shift, N * 128);
    }
    // ---- layer 1 ----
    {
        dim3 gg(Mpad / 128, 2);
        mfma_gemm_bt<128, 4><<<gg, 256, 0, stream>>>(zb, w1t, hb, as1, ad1, sv, dv, 256, 256);
        agg4_kernel<<<NB_AGG, 256, 0, stream>>>(hb, sv, dv, offsets, srcs, b1, zb, ps, pq, N);
        bn_final_kernel<<<1, 256, 0, stream>>>(ps, pq, g1, be1, scale, shift, N, 256, NB_AGG);
        bn_apply_kernel<256><<<256, 256, 0, stream>>>((uint*)zb, scale, shift, N * 128);
    }
    // ---- layer 2 (1 head, F=64); BN-apply fused into pool ----
    {
        dim3 gg(Mpad / 128, 1);
        mfma_gemm_bt<64, 1><<<gg, 256, 0, stream>>>(zb, w2t, hb, as2, ad2, sv, dv, 256, 64);
        agg1_kernel<<<NB_AGG, 256, 0, stream>>>(hb, sv, dv, offsets, srcs, b2, zb, ps, pq, N);
        bn_final_kernel<<<1, 64, 0, stream>>>(ps, pq, g2, be2, scale, shift, N, 64, NB_AGG);
    }

    // ---- pooling (BN+ReLU fused) + classifier ----
    pool_kernel<<<NB_POOL, 256, 0, stream>>>(zb, scale, shift, psum, pmax, N);
    classify_kernel<<<1, 128, 0, stream>>>(psum, pmax, Wc1, bc1, Wc2, bc2, out, N);
}

// Round 8
// 592.354 us; speedup vs baseline: 2.3249x; 2.3249x over previous
//
#include <hip/hip_runtime.h>

// ---------------------------------------------------------------------------
// GAT fraud detector, round 8:
//  - round 7 pipeline (persistent-wave agg with fused BN stats), but bn_final
//    parallelized: one block per channel, 256 threads stride the 1024 block
//    partials, LDS tree reduce. (round-7 bn_final was ONE block doing 1024
//    serial L2-latency iterations per thread -> 290us x3 = the regression)
// ---------------------------------------------------------------------------

typedef unsigned int uint;
typedef unsigned short ushort;

#define NEG_SLOPE 0.2f
#define BN_EPS 1e-5f
#define NB_AGG 1024   // persistent agg blocks (x4 waves = 4096 waves)
#define NB_POOL 256   // pool partial blocks

__device__ __forceinline__ float bf2f(uint u) { return __uint_as_float(u << 16); }
__device__ __forceinline__ ushort f2bf(float f) {
    uint u = __float_as_uint(f);
    u += 0x7fff + ((u >> 16) & 1);   // round-nearest-even
    return (ushort)(u >> 16);
}
__device__ __forceinline__ float lrelu(float x) { return x > 0.f ? x : NEG_SLOPE * x; }

// ---------------- fused prep: cvt x -> bf16 (padded), transpose weights, histogram ----------------

__global__ void prep_kernel(const float* __restrict__ x, ushort* __restrict__ xb,
                            int total_real, int total_pad,
                            const float* __restrict__ W0, ushort* __restrict__ w0t,
                            const float* __restrict__ W1, ushort* __restrict__ w1t,
                            const float* __restrict__ W2, ushort* __restrict__ w2t,
                            const int* __restrict__ ei, int* __restrict__ deg, int E) {
    int i = blockIdx.x * blockDim.x + threadIdx.x;
    if (i < total_pad) {
        xb[i] = (i < total_real) ? f2bf(x[i]) : (ushort)0;
        return;
    }
    int j = i - total_pad;
    if (j < 32768) {                        // W0: K=128,F=256
        int n = j / 128, k = j - n * 128;
        w0t[j] = f2bf(W0[(size_t)k * 256 + n]);
        return;
    }
    j -= 32768;
    if (j < 65536) {                        // W1: K=256,F=256
        int n = j / 256, k = j - n * 256;
        w1t[j] = f2bf(W1[(size_t)k * 256 + n]);
        return;
    }
    j -= 65536;
    if (j < 16384) {                        // W2: K=256,F=64
        int n = j / 256, k = j - n * 256;
        w2t[j] = f2bf(W2[(size_t)k * 64 + n]);
        return;
    }
    j -= 16384;
    if (j < E) atomicAdd(&deg[ei[E + j]], 1);
}

// ---------------- CSR scan + scatter ----------------

__global__ void scan_part(const int* __restrict__ deg, int* __restrict__ offsets,
                          int* __restrict__ bsum, int N) {
    __shared__ int sh[256];
    int t = threadIdx.x;
    int base = blockIdx.x * 1024 + t * 4;
    int v0 = (base + 0 < N) ? deg[base + 0] : 0;
    int v1 = (base + 1 < N) ? deg[base + 1] : 0;
    int v2 = (base + 2 < N) ? deg[base + 2] : 0;
    int v3 = (base + 3 < N) ? deg[base + 3] : 0;
    int s = v0 + v1 + v2 + v3;
    sh[t] = s;
    __syncthreads();
    for (int off = 1; off < 256; off <<= 1) {
        int y = (t >= off) ? sh[t - off] : 0;
        __syncthreads();
        sh[t] += y;
        __syncthreads();
    }
    int p = sh[t] - s;
    if (base + 0 < N) offsets[base + 0] = p;
    p += v0;
    if (base + 1 < N) offsets[base + 1] = p;
    p += v1;
    if (base + 2 < N) offsets[base + 2] = p;
    p += v2;
    if (base + 3 < N) offsets[base + 3] = p;
    if (t == 255) bsum[blockIdx.x] = sh[255];
}

__global__ void scan_add(int* __restrict__ offsets, int* __restrict__ cursor,
                         const int* __restrict__ bsum, int N) {
    __shared__ int sadd;
    int nb = gridDim.x;
    if (threadIdx.x == 0) {
        int run = 0;
        for (int b = 0; b < (int)blockIdx.x; ++b) run += bsum[b];
        sadd = run;
        if ((int)blockIdx.x == nb - 1) {
            int tot = run;
            for (int b = blockIdx.x; b < nb; ++b) tot += bsum[b];
            offsets[N] = tot;
        }
    }
    __syncthreads();
    int add = sadd;
    int base = blockIdx.x * 1024 + threadIdx.x * 4;
#pragma unroll
    for (int k = 0; k < 4; ++k) {
        int i = base + k;
        if (i < N) { int v = offsets[i] + add; offsets[i] = v; cursor[i] = v; }
    }
}

__global__ void scatter_kernel(const int* __restrict__ ei, int* __restrict__ cursor,
                               int* __restrict__ srcs, int E) {
    int e = blockIdx.x * blockDim.x + threadIdx.x;
    if (e < E) {
        int s = ei[e];
        int d = ei[E + e];
        int p = atomicAdd(&cursor[d], 1);
        srcs[p] = s;
    }
}

// ---------------- bf16 MFMA GEMM with fused sd epilogue ----------------

typedef __attribute__((ext_vector_type(8))) short bf16x8;
typedef __attribute__((ext_vector_type(4))) float floatx4;

template <int BN, int H>
__launch_bounds__(256)
__global__ void mfma_gemm_bt(const ushort* __restrict__ A, const ushort* __restrict__ Bt,
                             ushort* __restrict__ C, const float* __restrict__ asrc,
                             const float* __restrict__ adst, float* __restrict__ sv,
                             float* __restrict__ dv, int K, int Nn) {
    constexpr int WCOLS = (BN == 128) ? 2 : 1;
    constexpr int WROWS = 4 / WCOLS;
    constexpr int MT = 128 / (WROWS * 16);
    constexpr int NT = BN / (WCOLS * 16);
    constexpr int BCALLS = (BN * 32 * 2) / 4096;

    __shared__ ushort As[128 * 32];
    __shared__ ushort Bs[BN * 32];

    int t = threadIdx.x;
    int w = t >> 6, l = t & 63;
    int row0 = blockIdx.x * 128;
    int col0 = blockIdx.y * BN;
    int wr = (w / WCOLS) * (MT * 16);
    int wc = (w % WCOLS) * (NT * 16);

    floatx4 acc[MT][NT];
#pragma unroll
    for (int mi = 0; mi < MT; ++mi)
#pragma unroll
        for (int ni = 0; ni < NT; ++ni)
#pragma unroll
            for (int r = 0; r < 4; ++r) acc[mi][ni][r] = 0.f;

    int mrow = l & 15;
    int kc = (l >> 4) * 8;

    for (int kt = 0; kt < K; kt += 32) {
#pragma unroll
        for (int c = 0; c < 2; ++c) {
            int idx = c * 256 + t;
            const ushort* gp = A + (size_t)(row0 + (idx >> 2)) * K + kt + (idx & 3) * 8;
            __builtin_amdgcn_global_load_lds(
                (const __attribute__((address_space(1))) void*)gp,
                (__attribute__((address_space(3))) void*)(As + (idx & ~63) * 8),
                16, 0, 0);
        }
#pragma unroll
        for (int c = 0; c < BCALLS; ++c) {
            int idx = c * 256 + t;
            const ushort* gp = Bt + (size_t)(col0 + (idx >> 2)) * K + kt + (idx & 3) * 8;
            __builtin_amdgcn_global_load_lds(
                (const __attribute__((address_space(1))) void*)gp,
                (__attribute__((address_space(3))) void*)(Bs + (idx & ~63) * 8),
                16, 0, 0);
        }
        __syncthreads();

        bf16x8 af[MT], bfr[NT];
#pragma unroll
        for (int mi = 0; mi < MT; ++mi)
            af[mi] = *(const bf16x8*)&As[(wr + mi * 16 + mrow) * 32 + kc];
#pragma unroll
        for (int ni = 0; ni < NT; ++ni)
            bfr[ni] = *(const bf16x8*)&Bs[(wc + ni * 16 + mrow) * 32 + kc];
#pragma unroll
        for (int mi = 0; mi < MT; ++mi)
#pragma unroll
            for (int ni = 0; ni < NT; ++ni)
                acc[mi][ni] = __builtin_amdgcn_mfma_f32_16x16x32_bf16(
                    af[mi], bfr[ni], acc[mi][ni], 0, 0, 0);
        __syncthreads();
    }

    // C store (C/D layout: col=lane&15, row=(lane>>4)*4+reg)
#pragma unroll
    for (int mi = 0; mi < MT; ++mi) {
        int rbase = row0 + wr + mi * 16 + (l >> 4) * 4;
#pragma unroll
        for (int ni = 0; ni < NT; ++ni) {
            int col = col0 + wc + ni * 16 + (l & 15);
#pragma unroll
            for (int r = 0; r < 4; ++r)
                C[(size_t)(rbase + r) * Nn + col] = f2bf(acc[mi][ni][r]);
        }
    }

    // fused sd: this wave's NT*16 cols lie in exactly one head (64 cols).
    float av[NT], bv[NT];
#pragma unroll
    for (int ni = 0; ni < NT; ++ni) {
        int ch = col0 + wc + ni * 16 + (l & 15);
        av[ni] = asrc[ch];
        bv[ni] = adst[ch];
    }
    int gh = (col0 + wc) >> 6;
#pragma unroll
    for (int mi = 0; mi < MT; ++mi) {
#pragma unroll
        for (int r = 0; r < 4; ++r) {
            float s = 0.f, d = 0.f;
#pragma unroll
            for (int ni = 0; ni < NT; ++ni) {
                float hv = acc[mi][ni][r];
                s += hv * av[ni];
                d += hv * bv[ni];
            }
#pragma unroll
            for (int m = 8; m >= 1; m >>= 1) {
                s += __shfl_xor(s, m);
                d += __shfl_xor(d, m);
            }
            if ((l & 15) == 0) {
                int row = row0 + wr + mi * 16 + (l >> 4) * 4 + r;
                sv[row * H + gh] = s;
                dv[row * H + gh] = d;
            }
        }
    }
}

// ---------------- aggregation: persistent waves, one node per wave ----------------
// Wave = 2 edge-slots x 32 lanes; lane owns 8 channels (uint4/edge). Slots
// combined by shfl_xor(32). BN stats accumulated in registers across nodes,
// flushed once per block via LDS -> per-block partials ps/pq.

__launch_bounds__(256)
__global__ void agg4_kernel(const ushort* __restrict__ hb, const float* __restrict__ sv,
                            const float* __restrict__ dv, const int* __restrict__ offsets,
                            const int* __restrict__ srcs, const float* __restrict__ bias,
                            ushort* __restrict__ zb, float* __restrict__ ps,
                            float* __restrict__ pq, int N) {
    __shared__ float lds_s[256], lds_q[256];
    int t = threadIdx.x;
    lds_s[t] = 0.f; lds_q[t] = 0.f;
    __syncthreads();

    int l = t & 63;
    int half = l >> 5, gl = l & 31, head = gl >> 3;
    int cbase = gl * 8;
    int gw = blockIdx.x * 4 + (t >> 6);
    int nw = gridDim.x * 4;

    float bi[8];
    *(float4*)&bi[0] = *(const float4*)&bias[cbase];
    *(float4*)&bi[4] = *(const float4*)&bias[cbase + 4];

    float szm[8] = {}, sqm[8] = {};

    for (int i = gw; i < N; i += nw) {
        int beg = offsets[i], end = offsets[i + 1];
        float d_i = dv[i * 4 + head];
        float acc[8] = {};
        float den = 0.f;

        int j0 = beg + half, j1 = j0 + 2;
        while (j1 < end) {
            int s0 = srcs[j0], s1 = srcs[j1];
            float sv0 = sv[s0 * 4 + head], sv1 = sv[s1 * 4 + head];
            uint4 q0 = *(const uint4*)&hb[(size_t)s0 * 256 + cbase];
            uint4 q1 = *(const uint4*)&hb[(size_t)s1 * 256 + cbase];
            float w0 = __expf(fminf(lrelu(sv0 + d_i), 60.f));
            float w1 = __expf(fminf(lrelu(sv1 + d_i), 60.f));
            den += w0 + w1;
            uint pr0[4] = {q0.x, q0.y, q0.z, q0.w};
            uint pr1[4] = {q1.x, q1.y, q1.z, q1.w};
#pragma unroll
            for (int k = 0; k < 4; ++k) {
                acc[2 * k]     += w0 * bf2f(pr0[k] & 0xffffu) + w1 * bf2f(pr1[k] & 0xffffu);
                acc[2 * k + 1] += w0 * bf2f(pr0[k] >> 16)     + w1 * bf2f(pr1[k] >> 16);
            }
            j0 += 4; j1 += 4;
        }
        if (j0 < end) {
            int s0 = srcs[j0];
            float sv0 = sv[s0 * 4 + head];
            uint4 q0 = *(const uint4*)&hb[(size_t)s0 * 256 + cbase];
            float w0 = __expf(fminf(lrelu(sv0 + d_i), 60.f));
            den += w0;
            uint pr0[4] = {q0.x, q0.y, q0.z, q0.w};
#pragma unroll
            for (int k = 0; k < 4; ++k) {
                acc[2 * k]     += w0 * bf2f(pr0[k] & 0xffffu);
                acc[2 * k + 1] += w0 * bf2f(pr0[k] >> 16);
            }
        }

        den += __shfl_xor(den, 32);
#pragma unroll
        for (int k = 0; k < 8; ++k) acc[k] += __shfl_xor(acc[k], 32);

        float wself = __expf(fminf(lrelu(sv[i * 4 + head] + d_i), 60.f));
        uint4 qs = *(const uint4*)&hb[(size_t)i * 256 + cbase];
        float rden = 1.f / (den + wself + 1e-16f);
        uint prs[4] = {qs.x, qs.y, qs.z, qs.w};
        float out[8];
#pragma unroll
        for (int k = 0; k < 4; ++k) {
            out[2 * k]     = (acc[2 * k]     + wself * bf2f(prs[k] & 0xffffu)) * rden + bi[2 * k];
            out[2 * k + 1] = (acc[2 * k + 1] + wself * bf2f(prs[k] >> 16))     * rden + bi[2 * k + 1];
        }
#pragma unroll
        for (int k = 0; k < 8; ++k) { szm[k] += out[k]; sqm[k] += out[k] * out[k]; }
        if (half == 0) {
            uint4 o;
            o.x = (uint)f2bf(out[0]) | ((uint)f2bf(out[1]) << 16);
            o.y = (uint)f2bf(out[2]) | ((uint)f2bf(out[3]) << 16);
            o.z = (uint)f2bf(out[4]) | ((uint)f2bf(out[5]) << 16);
            o.w = (uint)f2bf(out[6]) | ((uint)f2bf(out[7]) << 16);
            *(uint4*)&zb[(size_t)i * 256 + cbase] = o;
        }
    }

    if (half == 0) {
#pragma unroll
        for (int k = 0; k < 8; ++k) {
            atomicAdd(&lds_s[cbase + k], szm[k]);
            atomicAdd(&lds_q[cbase + k], sqm[k]);
        }
    }
    __syncthreads();
    ps[blockIdx.x * 256 + t] = lds_s[t];
    pq[blockIdx.x * 256 + t] = lds_q[t];
}

// H=1, F=64: wave = 4 slots x 16 lanes (uint2/edge), combine shfl 16 then 32.

__launch_bounds__(256)
__global__ void agg1_kernel(const ushort* __restrict__ hb, const float* __restrict__ sv,
                            const float* __restrict__ dv, const int* __restrict__ offsets,
                            const int* __restrict__ srcs, const float* __restrict__ bias,
                            ushort* __restrict__ zb, float* __restrict__ ps,
                            float* __restrict__ pq, int N) {
    __shared__ float lds_s[64], lds_q[64];
    int t = threadIdx.x;
    if (t < 64) { lds_s[t] = 0.f; lds_q[t] = 0.f; }
    __syncthreads();

    int l = t & 63;
    int slot = l >> 4, gl = l & 15;
    int cbase = gl * 4;
    int gw = blockIdx.x * 4 + (t >> 6);
    int nw = gridDim.x * 4;

    float bi[4];
    *(float4*)&bi[0] = *(const float4*)&bias[cbase];

    float szm[4] = {}, sqm[4] = {};

    for (int i = gw; i < N; i += nw) {
        int beg = offsets[i], end = offsets[i + 1];
        float d_i = dv[i];
        float acc[4] = {};
        float den = 0.f;

        int j0 = beg + slot, j1 = j0 + 4;
        while (j1 < end) {
            int s0 = srcs[j0], s1 = srcs[j1];
            float sv0 = sv[s0], sv1 = sv[s1];
            uint2 q0 = *(const uint2*)&hb[(size_t)s0 * 64 + cbase];
            uint2 q1 = *(const uint2*)&hb[(size_t)s1 * 64 + cbase];
            float w0 = __expf(fminf(lrelu(sv0 + d_i), 60.f));
            float w1 = __expf(fminf(lrelu(sv1 + d_i), 60.f));
            den += w0 + w1;
            acc[0] += w0 * bf2f(q0.x & 0xffffu) + w1 * bf2f(q1.x & 0xffffu);
            acc[1] += w0 * bf2f(q0.x >> 16)     + w1 * bf2f(q1.x >> 16);
            acc[2] += w0 * bf2f(q0.y & 0xffffu) + w1 * bf2f(q1.y & 0xffffu);
            acc[3] += w0 * bf2f(q0.y >> 16)     + w1 * bf2f(q1.y >> 16);
            j0 += 8; j1 += 8;
        }
        if (j0 < end) {
            int s0 = srcs[j0];
            float sv0 = sv[s0];
            uint2 q0 = *(const uint2*)&hb[(size_t)s0 * 64 + cbase];
            float w0 = __expf(fminf(lrelu(sv0 + d_i), 60.f));
            den += w0;
            acc[0] += w0 * bf2f(q0.x & 0xffffu);
            acc[1] += w0 * bf2f(q0.x >> 16);
            acc[2] += w0 * bf2f(q0.y & 0xffffu);
            acc[3] += w0 * bf2f(q0.y >> 16);
        }

#pragma unroll
        for (int k = 0; k < 4; ++k) {
            acc[k] += __shfl_xor(acc[k], 16);
            acc[k] += __shfl_xor(acc[k], 32);
        }
        den += __shfl_xor(den, 16);
        den += __shfl_xor(den, 32);

        float wself = __expf(fminf(lrelu(sv[i] + d_i), 60.f));
        uint2 qs = *(const uint2*)&hb[(size_t)i * 64 + cbase];
        float rden = 1.f / (den + wself + 1e-16f);
        float out[4];
        out[0] = (acc[0] + wself * bf2f(qs.x & 0xffffu)) * rden + bi[0];
        out[1] = (acc[1] + wself * bf2f(qs.x >> 16))     * rden + bi[1];
        out[2] = (acc[2] + wself * bf2f(qs.y & 0xffffu)) * rden + bi[2];
        out[3] = (acc[3] + wself * bf2f(qs.y >> 16))     * rden + bi[3];
#pragma unroll
        for (int k = 0; k < 4; ++k) { szm[k] += out[k]; sqm[k] += out[k] * out[k]; }
        if (slot == 0) {
            uint2 o;
            o.x = (uint)f2bf(out[0]) | ((uint)f2bf(out[1]) << 16);
            o.y = (uint)f2bf(out[2]) | ((uint)f2bf(out[3]) << 16);
            *(uint2*)&zb[(size_t)i * 64 + cbase] = o;
        }
    }

    if (slot == 0 && (l >> 4) == 0) {
#pragma unroll
        for (int k = 0; k < 4; ++k) {
            atomicAdd(&lds_s[cbase + k], szm[k]);
            atomicAdd(&lds_q[cbase + k], sqm[k]);
        }
    }
    __syncthreads();
    if (t < 64) {
        ps[blockIdx.x * 64 + t] = lds_s[t];
        pq[blockIdx.x * 64 + t] = lds_q[t];
    }
}

// ---------------- BN final: PARALLEL partial reduce (one block per channel) ----------------

__launch_bounds__(256)
__global__ void bn_final_kernel(const float* __restrict__ ps, const float* __restrict__ pq,
                                const float* __restrict__ g, const float* __restrict__ be,
                                float* __restrict__ scale, float* __restrict__ shift,
                                int N, int F) {
    __shared__ float sh_s[256], sh_q[256];
    int c = blockIdx.x;          // channel
    int t = threadIdx.x;
    float s = 0.f, q = 0.f;
    for (int b = t; b < NB_AGG; b += 256) {
        s += ps[(size_t)b * F + c];
        q += pq[(size_t)b * F + c];
    }
    sh_s[t] = s; sh_q[t] = q;
    __syncthreads();
    for (int off = 128; off >= 1; off >>= 1) {
        if (t < off) { sh_s[t] += sh_s[t + off]; sh_q[t] += sh_q[t + off]; }
        __syncthreads();
    }
    if (t == 0) {
        float mean = sh_s[0] / (float)N;
        float var = sh_q[0] / (float)N - mean * mean;
        float sc = g[c] * rsqrtf(var + BN_EPS);
        scale[c] = sc;
        shift[c] = be[c] - sc * mean;
    }
}

template <int F>
__launch_bounds__(256)
__global__ void bn_apply_kernel(uint* __restrict__ x, const float* __restrict__ scale,
                                const float* __restrict__ shift, int totalPairs) {
    __shared__ float ssc[F], ssh[F];
    int t = threadIdx.x;
    if (t < F) { ssc[t] = scale[t]; ssh[t] = shift[t]; }
    __syncthreads();
    for (int i = blockIdx.x * 256 + t; i < totalPairs; i += gridDim.x * 256) {
        uint p = x[i];
        int c0 = (2 * i) & (F - 1);
        float v0 = fmaxf(bf2f(p & 0xffffu) * ssc[c0] + ssh[c0], 0.f);
        float v1 = fmaxf(bf2f(p >> 16) * ssc[c0 + 1] + ssh[c0 + 1], 0.f);
        x[i] = (uint)f2bf(v0) | ((uint)f2bf(v1) << 16);
    }
}

// ---------------- pooling (BN+ReLU fused, vectorized) ----------------

__launch_bounds__(256)
__global__ void pool_kernel(const ushort* __restrict__ y, const float* __restrict__ scale,
                            const float* __restrict__ shift, float* __restrict__ psum,
                            float* __restrict__ pmax, int N) {
    constexpr int F = 64, OCT = 8;
    __shared__ float lds_s[F];
    __shared__ uint lds_m[F];
    int t = threadIdx.x;
    if (t < F) { lds_s[t] = 0.f; lds_m[t] = 0u; }
    __syncthreads();

    int co = t % OCT;
    float sc[8], sh[8];
#pragma unroll
    for (int j = 0; j < 8; ++j) { sc[j] = scale[co * 8 + j]; sh[j] = shift[co * 8 + j]; }

    float s[8] = {}, m[8] = {};
    int total8 = N * F / 8;
    for (int idx = blockIdx.x * 256 + t; idx < total8; idx += NB_POOL * 256) {
        uint4 v = ((const uint4*)y)[idx];
        uint pr[4] = {v.x, v.y, v.z, v.w};
#pragma unroll
        for (int k = 0; k < 4; ++k) {
            float a = fmaxf(bf2f(pr[k] & 0xffffu) * sc[2 * k] + sh[2 * k], 0.f);
            float b = fmaxf(bf2f(pr[k] >> 16) * sc[2 * k + 1] + sh[2 * k + 1], 0.f);
            s[2 * k] += a;     m[2 * k] = fmaxf(m[2 * k], a);
            s[2 * k + 1] += b; m[2 * k + 1] = fmaxf(m[2 * k + 1], b);
        }
    }
#pragma unroll
    for (int j = 0; j < 8; ++j) {
        atomicAdd(&lds_s[co * 8 + j], s[j]);
        atomicMax(&lds_m[co * 8 + j], __float_as_uint(m[j]));
    }
    __syncthreads();
    if (t < F) {
        psum[blockIdx.x * F + t] = lds_s[t];
        pmax[blockIdx.x * F + t] = __uint_as_float(lds_m[t]);
    }
}

__global__ void classify_kernel(const float* __restrict__ psum, const float* __restrict__ pmax,
                                const float* __restrict__ Wc1, const float* __restrict__ bc1,
                                const float* __restrict__ Wc2, const float* __restrict__ bc2,
                                float* __restrict__ out, int N) {
    __shared__ float pooled[128];
    __shared__ float z[64];
    int t = threadIdx.x;   // 128 threads
    if (t < 64) {
        float s = 0.f;
        for (int b = 0; b < NB_POOL; ++b) s += psum[b * 64 + t];
        pooled[t] = s / (float)N;
    } else {
        int c = t - 64;
        float m = 0.f;
        for (int b = 0; b < NB_POOL; ++b) m = fmaxf(m, pmax[b * 64 + c]);
        pooled[t] = m;
    }
    __syncthreads();
    if (t < 64) {
        float a = bc1[t];
        for (int k = 0; k < 128; ++k) a += pooled[k] * Wc1[k * 64 + t];
        z[t] = a > 0.f ? a : 0.f;
    }
    __syncthreads();
    if (t < 2) {
        float a = bc2[t];
        for (int j = 0; j < 64; ++j) a += z[j] * Wc2[j * 2 + t];
        out[t] = a;
    }
}

// ---------------- driver ----------------

extern "C" void kernel_launch(void* const* d_in, const int* in_sizes, int n_in,
                              void* d_out, int out_size, void* d_ws, size_t ws_size,
                              hipStream_t stream) {
    const float* x   = (const float*)d_in[0];
    const int*   ei  = (const int*)d_in[1];
    const float* W0  = (const float*)d_in[2];  const float* b0  = (const float*)d_in[3];
    const float* as0 = (const float*)d_in[4];  const float* ad0 = (const float*)d_in[5];
    const float* g0  = (const float*)d_in[6];  const float* be0 = (const float*)d_in[7];
    const float* W1  = (const float*)d_in[8];  const float* b1  = (const float*)d_in[9];
    const float* as1 = (const float*)d_in[10]; const float* ad1 = (const float*)d_in[11];
    const float* g1  = (const float*)d_in[12]; const float* be1 = (const float*)d_in[13];
    const float* W2  = (const float*)d_in[14]; const float* b2  = (const float*)d_in[15];
    const float* as2 = (const float*)d_in[16]; const float* ad2 = (const float*)d_in[17];
    const float* g2  = (const float*)d_in[18]; const float* be2 = (const float*)d_in[19];
    const float* Wc1 = (const float*)d_in[20]; const float* bc1 = (const float*)d_in[21];
    const float* Wc2 = (const float*)d_in[22]; const float* bc2 = (const float*)d_in[23];
    float* out = (float*)d_out;

    const int N = in_sizes[0] / 128;            // 50000
    const int E = in_sizes[1] / 2;              // 800000
    const int Mpad = ((N + 127) / 128) * 128;   // 50048
    const int NB_SCAN = (N + 1023) / 1024;      // 49

    char* ws = (char*)d_ws;
    size_t o = 0;
    auto alloc = [&](size_t bytes) -> void* {
        void* p = ws + o;
        o = (o + bytes + 255) & ~(size_t)255;
        return p;
    };
    int*    deg     = (int*)alloc((size_t)N * 4);
    int*    offsets = (int*)alloc((size_t)(N + 1) * 4);
    int*    cursor  = (int*)alloc((size_t)N * 4);
    int*    srcs    = (int*)alloc((size_t)E * 4);
    int*    bsum    = (int*)alloc((size_t)NB_SCAN * 4);
    ushort* xb      = (ushort*)alloc((size_t)Mpad * 128 * 2);
    ushort* w0t     = (ushort*)alloc((size_t)256 * 128 * 2);
    ushort* w1t     = (ushort*)alloc((size_t)256 * 256 * 2);
    ushort* w2t     = (ushort*)alloc((size_t)64 * 256 * 2);
    ushort* hb      = (ushort*)alloc((size_t)Mpad * 256 * 2);
    ushort* zb      = (ushort*)alloc((size_t)Mpad * 256 * 2);
    float*  sv      = (float*)alloc((size_t)Mpad * 4 * 4);
    float*  dv      = (float*)alloc((size_t)Mpad * 4 * 4);
    float*  ps      = (float*)alloc((size_t)NB_AGG * 256 * 4);
    float*  pq      = (float*)alloc((size_t)NB_AGG * 256 * 4);
    float*  scale   = (float*)alloc(256 * 4);
    float*  shift   = (float*)alloc(256 * 4);
    float*  psum    = (float*)alloc((size_t)NB_POOL * 64 * 4);
    float*  pmax    = (float*)alloc((size_t)NB_POOL * 64 * 4);

    // ---- prep (cvt + transpose + histogram) ----
    hipMemsetAsync(deg, 0, (size_t)N * 4, stream);
    int prep_total = Mpad * 128 + 32768 + 65536 + 16384 + E;
    prep_kernel<<<(prep_total + 255) / 256, 256, 0, stream>>>(
        x, xb, N * 128, Mpad * 128, W0, w0t, W1, w1t, W2, w2t, ei, deg, E);

    // ---- CSR scan + scatter ----
    scan_part<<<NB_SCAN, 256, 0, stream>>>(deg, offsets, bsum, N);
    scan_add<<<NB_SCAN, 256, 0, stream>>>(offsets, cursor, bsum, N);
    scatter_kernel<<<(E + 255) / 256, 256, 0, stream>>>(ei, cursor, srcs, E);

    // ---- layer 0 ----
    {
        dim3 gg(Mpad / 128, 2);
        mfma_gemm_bt<128, 4><<<gg, 256, 0, stream>>>(xb, w0t, hb, as0, ad0, sv, dv, 128, 256);
        agg4_kernel<<<NB_AGG, 256, 0, stream>>>(hb, sv, dv, offsets, srcs, b0, zb, ps, pq, N);
        bn_final_kernel<<<256, 256, 0, stream>>>(ps, pq, g0, be0, scale, shift, N, 256);
        bn_apply_kernel<256><<<256, 256, 0, stream>>>((uint*)zb, scale, shift, N * 128);
    }
    // ---- layer 1 ----
    {
        dim3 gg(Mpad / 128, 2);
        mfma_gemm_bt<128, 4><<<gg, 256, 0, stream>>>(zb, w1t, hb, as1, ad1, sv, dv, 256, 256);
        agg4_kernel<<<NB_AGG, 256, 0, stream>>>(hb, sv, dv, offsets, srcs, b1, zb, ps, pq, N);
        bn_final_kernel<<<256, 256, 0, stream>>>(ps, pq, g1, be1, scale, shift, N, 256);
        bn_apply_kernel<256><<<256, 256, 0, stream>>>((uint*)zb, scale, shift, N * 128);
    }
    // ---- layer 2 (1 head, F=64); BN-apply fused into pool ----
    {
        dim3 gg(Mpad / 128, 1);
        mfma_gemm_bt<64, 1><<<gg, 256, 0, stream>>>(zb, w2t, hb, as2, ad2, sv, dv, 256, 64);
        agg1_kernel<<<NB_AGG, 256, 0, stream>>>(hb, sv, dv, offsets, srcs, b2, zb, ps, pq, N);
        bn_final_kernel<<<64, 256, 0, stream>>>(ps, pq, g2, be2, scale, shift, N, 64);
    }

    // ---- pooling (BN+ReLU fused) + classifier ----
    pool_kernel<<<NB_POOL, 256, 0, stream>>>(zb, scale, shift, psum, pmax, N);
    classify_kernel<<<1, 128, 0, stream>>>(psum, pmax, Wc1, bc1, Wc2, bc2, out, N);
}